// Round 8
// baseline (786.455 us; speedup 1.0000x reference)
//
#include <hip/hip_runtime.h>

// LightGCN propagation on MI355X — R7 (= R6 + compile fix): NT streaming loads,
// acc-RMW elimination (fold into final layer), 8-lane/row ushort8 SpMM.
//
// R6 failed to compile: __builtin_nontemporal_load requires clang vector types,
// not HIP_vector_type (float4). k_init now uses ext_vector_type(4) float.
//
// Inputs: [2] adj_src (6M int), [3] adj_dst (6M int), [4] adj_vals (6M f32),
//         [5] user_emb (100000x64 f32), [6] item_emb (50000x64 f32).
// Output: [150000x64] f32 = (e0+e1+e2+e3)/4.

#define NUM_USERS 100000
#define NUM_ITEMS 50000
#define N_NODES   150000
#define EMB       64
#define N_EDGES   6000000

#define ROWS_PER_B 256
#define NBUCKETS   586                        // ceil(150000/256)
#define NROWS_PAD  (NBUCKETS * ROWS_PER_B)    // 150016
#define PART_BLOCKS 512
#define CHUNK ((N_EDGES + PART_BLOCKS - 1) / PART_BLOCKS)   // 11719

constexpr int NODE_F4 = N_NODES * EMB / 4;   // 2,400,000
constexpr int USER_F4 = NUM_USERS * EMB / 4; // 1,600,000

typedef unsigned short us8 __attribute__((ext_vector_type(8)));   // 16B
typedef float f4v __attribute__((ext_vector_type(4)));            // 16B clang vector

__device__ __forceinline__ float bf2f(unsigned short u) {
    union { unsigned int i; float f; } x; x.i = ((unsigned int)u) << 16; return x.f;
}
__device__ __forceinline__ unsigned short f2bf(float f) {
    union { float f; unsigned int i; } x; x.f = f;
    unsigned int b = x.i;
    return (unsigned short)((b + 0x7FFFu + ((b >> 16) & 1u)) >> 16);  // RNE
}

// ---------------- phase 0: bucket histogram + scan ----------------

__global__ void k_zero(int* __restrict__ p, int n) {
    int i = blockIdx.x * blockDim.x + threadIdx.x;
    if (i < n) p[i] = 0;
}

__global__ __launch_bounds__(256) void k_bhist(const int* __restrict__ dst,
                                               int* __restrict__ gcnt) {
    __shared__ int cnt[NBUCKETS];
    int t = threadIdx.x;
    for (int i = t; i < NBUCKETS; i += 256) cnt[i] = 0;
    __syncthreads();
    int e0 = blockIdx.x * CHUNK;
    int e1 = min(e0 + CHUNK, N_EDGES);
    int e = e0 + t;
    for (; e + 256 < e1; e += 512) {
        int b0 = __builtin_nontemporal_load(dst + e) >> 8;
        int b1 = __builtin_nontemporal_load(dst + e + 256) >> 8;
        atomicAdd(&cnt[b0], 1);               // native ds_add_u32
        atomicAdd(&cnt[b1], 1);
    }
    if (e < e1) atomicAdd(&cnt[__builtin_nontemporal_load(dst + e) >> 8], 1);
    __syncthreads();
    for (int i = t; i < NBUCKETS; i += 256)
        if (cnt[i]) atomicAdd(&gcnt[i], cnt[i]);
}

__global__ void k_bscan(const int* __restrict__ gcnt, int* __restrict__ boff,
                        int* __restrict__ gcur) {
    __shared__ int s[1024];
    int t = threadIdx.x;
    int x = (t < NBUCKETS) ? gcnt[t] : 0;
    s[t] = x;
    __syncthreads();
    for (int off = 1; off < 1024; off <<= 1) {
        int v = (t >= off) ? s[t - off] : 0;
        __syncthreads();
        s[t] += v;
        __syncthreads();
    }
    if (t < NBUCKETS) { int ex = s[t] - x; boff[t] = ex; gcur[t] = ex; }
    if (t == 0) boff[NBUCKETS] = N_EDGES;
}

// ---------------- phase 1: bucket partition ----------------
// entry: x = src | (dstLocal<<18), y = val bits

__global__ __launch_bounds__(256) void k_part(const int* __restrict__ src,
                                              const int* __restrict__ dst,
                                              const float* __restrict__ val,
                                              int* __restrict__ gcur,
                                              int2* __restrict__ pairs) {
    __shared__ int cnt[NBUCKETS];
    __shared__ int base[NBUCKETS];
    int t = threadIdx.x;
    for (int i = t; i < NBUCKETS; i += 256) cnt[i] = 0;
    __syncthreads();
    int e0 = blockIdx.x * CHUNK;
    int e1 = min(e0 + CHUNK, N_EDGES);
    {
        int e = e0 + t;
        for (; e + 256 < e1; e += 512) {
            int b0 = __builtin_nontemporal_load(dst + e) >> 8;
            int b1 = __builtin_nontemporal_load(dst + e + 256) >> 8;
            atomicAdd(&cnt[b0], 1);
            atomicAdd(&cnt[b1], 1);
        }
        if (e < e1) atomicAdd(&cnt[__builtin_nontemporal_load(dst + e) >> 8], 1);
    }
    __syncthreads();
    for (int i = t; i < NBUCKETS; i += 256) {
        int c = cnt[i];
        base[i] = c ? atomicAdd(&gcur[i], c) : 0;
        cnt[i] = 0;
    }
    __syncthreads();
    {
        int e = e0 + t;
        for (; e + 256 < e1; e += 512) {
            int d0 = __builtin_nontemporal_load(dst + e);
            int s0 = __builtin_nontemporal_load(src + e);
            float v0 = __builtin_nontemporal_load(val + e);
            int d1 = __builtin_nontemporal_load(dst + e + 256);
            int s1 = __builtin_nontemporal_load(src + e + 256);
            float v1 = __builtin_nontemporal_load(val + e + 256);
            int b0 = d0 >> 8, b1 = d1 >> 8;
            int o0 = atomicAdd(&cnt[b0], 1);
            int o1 = atomicAdd(&cnt[b1], 1);
            pairs[base[b0] + o0] = make_int2(s0 | ((d0 & 255) << 18), __float_as_int(v0));
            pairs[base[b1] + o1] = make_int2(s1 | ((d1 & 255) << 18), __float_as_int(v1));
        }
        if (e < e1) {
            int d0 = __builtin_nontemporal_load(dst + e);
            int s0 = __builtin_nontemporal_load(src + e);
            float v0 = __builtin_nontemporal_load(val + e);
            int o0 = atomicAdd(&cnt[d0 >> 8], 1);
            pairs[base[d0 >> 8] + o0] = make_int2(s0 | ((d0 & 255) << 18),
                                                  __float_as_int(v0));
        }
    }
}

// ---------------- phase 2: per-bucket row histogram + scan + placement ----------------

__global__ __launch_bounds__(256) void k_sort(const int* __restrict__ boff,
                                              const int2* __restrict__ pairs1,
                                              int2* __restrict__ pairs2,
                                              int* __restrict__ row_ptr) {
    __shared__ int cnt[ROWS_PER_B];    // counts, then cursors
    __shared__ int s[ROWS_PER_B];
    int b = blockIdx.x;
    int t = threadIdx.x;
    cnt[t] = 0;
    __syncthreads();
    int beg = boff[b], end = boff[b + 1];
    {
        int e = beg + t;
        for (; e + 256 < end; e += 512) {
            int r0 = ((unsigned)pairs1[e].x) >> 18;   // normal load: reused by pass 2
            int r1 = ((unsigned)pairs1[e + 256].x) >> 18;
            atomicAdd(&cnt[r0], 1);
            atomicAdd(&cnt[r1], 1);
        }
        if (e < end) atomicAdd(&cnt[((unsigned)pairs1[e].x) >> 18], 1);
    }
    __syncthreads();
    int x = cnt[t];
    s[t] = x;
    __syncthreads();
    for (int off = 1; off < 256; off <<= 1) {
        int v = (t >= off) ? s[t - off] : 0;
        __syncthreads();
        s[t] += v;
        __syncthreads();
    }
    int ex = beg + s[t] - x;
    row_ptr[b * ROWS_PER_B + t] = ex;
    if (b == NBUCKETS - 1 && t == 255) row_ptr[NROWS_PAD] = N_EDGES;
    __syncthreads();
    cnt[t] = ex;
    __syncthreads();
    const long* p1l = (const long*)pairs1;
    {
        int e = beg + t;
        for (; e + 256 < end; e += 512) {
            long q0 = __builtin_nontemporal_load(p1l + e);          // last read: NT
            long q1 = __builtin_nontemporal_load(p1l + e + 256);
            int x0 = (int)q0, y0 = (int)(q0 >> 32);
            int x1 = (int)q1, y1 = (int)(q1 >> 32);
            int pos0 = atomicAdd(&cnt[((unsigned)x0) >> 18], 1);
            int pos1 = atomicAdd(&cnt[((unsigned)x1) >> 18], 1);
            pairs2[pos0] = make_int2(x0 & 0x3FFFF, y0);
            pairs2[pos1] = make_int2(x1 & 0x3FFFF, y1);
        }
        if (e < end) {
            long q0 = __builtin_nontemporal_load(p1l + e);
            int x0 = (int)q0, y0 = (int)(q0 >> 32);
            int pos0 = atomicAdd(&cnt[((unsigned)x0) >> 18], 1);
            pairs2[pos0] = make_int2(x0 & 0x3FFFF, y0);
        }
    }
}

// ---------------- phase 3: propagation ----------------

__global__ void k_init(const f4v* __restrict__ ue, const f4v* __restrict__ ie,
                       ushort4* __restrict__ e0b, f4v* __restrict__ acc) {
    int i = blockIdx.x * blockDim.x + threadIdx.x;
    if (i >= NODE_F4) return;
    f4v v = (i < USER_F4) ? __builtin_nontemporal_load(ue + i)
                          : __builtin_nontemporal_load(ie + i - USER_F4);
    __builtin_nontemporal_store(v, acc + i);     // re-read only at the very end
    e0b[i] = make_ushort4(f2bf(v.x), f2bf(v.y), f2bf(v.z), f2bf(v.w));
}

// 8 lanes per row; lane owns 8 channels (16B ushort8 gather). Layers 0/1:
// nxt = sum_k val_k * cur[src_k] only (no acc traffic).
__global__ __launch_bounds__(256) void k_spmm(const int* __restrict__ row_ptr,
                                              const long* __restrict__ pairs,
                                              const us8* __restrict__ cur,
                                              us8* __restrict__ nxt) {
    int tid = blockIdx.x * blockDim.x + threadIdx.x;
    int row = tid >> 3;
    if (row >= N_NODES) return;
    int c = tid & 7;
    int beg = row_ptr[row];
    int end = row_ptr[row + 1];
    float r[8];
#pragma unroll
    for (int j = 0; j < 8; ++j) r[j] = 0.f;
    int k = beg;
    for (; k + 3 < end; k += 4) {
        long p0 = __builtin_nontemporal_load(pairs + k);
        long p1 = __builtin_nontemporal_load(pairs + k + 1);
        long p2 = __builtin_nontemporal_load(pairs + k + 2);
        long p3 = __builtin_nontemporal_load(pairs + k + 3);
        us8 g0 = cur[(long)(int)(p0 & 0x3FFFF) * 8 + c];
        us8 g1 = cur[(long)(int)(p1 & 0x3FFFF) * 8 + c];
        us8 g2 = cur[(long)(int)(p2 & 0x3FFFF) * 8 + c];
        us8 g3 = cur[(long)(int)(p3 & 0x3FFFF) * 8 + c];
        float v0 = __int_as_float((int)(p0 >> 32));
        float v1 = __int_as_float((int)(p1 >> 32));
        float v2 = __int_as_float((int)(p2 >> 32));
        float v3 = __int_as_float((int)(p3 >> 32));
#pragma unroll
        for (int j = 0; j < 8; ++j)
            r[j] += v0 * bf2f(g0[j]) + v1 * bf2f(g1[j])
                  + v2 * bf2f(g2[j]) + v3 * bf2f(g3[j]);
    }
    for (; k < end; ++k) {
        long p0 = __builtin_nontemporal_load(pairs + k);
        us8 g0 = cur[(long)(int)(p0 & 0x3FFFF) * 8 + c];
        float v0 = __int_as_float((int)(p0 >> 32));
#pragma unroll
        for (int j = 0; j < 8; ++j) r[j] += v0 * bf2f(g0[j]);
    }
    us8 o;
#pragma unroll
    for (int j = 0; j < 8; ++j) o[j] = f2bf(r[j]);
    nxt[(long)row * 8 + c] = o;
}

// Final layer: r = SpMM(e2); acc = (acc + e1 + e2 + r) * 0.25
__global__ __launch_bounds__(256) void k_spmm_fin(const int* __restrict__ row_ptr,
                                                  const long* __restrict__ pairs,
                                                  const us8* __restrict__ cur,   // e2b
                                                  const us8* __restrict__ e1b,
                                                  float4* __restrict__ acc) {
    int tid = blockIdx.x * blockDim.x + threadIdx.x;
    int row = tid >> 3;
    if (row >= N_NODES) return;
    int c = tid & 7;
    int beg = row_ptr[row];
    int end = row_ptr[row + 1];
    float r[8];
#pragma unroll
    for (int j = 0; j < 8; ++j) r[j] = 0.f;
    int k = beg;
    for (; k + 3 < end; k += 4) {
        long p0 = __builtin_nontemporal_load(pairs + k);
        long p1 = __builtin_nontemporal_load(pairs + k + 1);
        long p2 = __builtin_nontemporal_load(pairs + k + 2);
        long p3 = __builtin_nontemporal_load(pairs + k + 3);
        us8 g0 = cur[(long)(int)(p0 & 0x3FFFF) * 8 + c];
        us8 g1 = cur[(long)(int)(p1 & 0x3FFFF) * 8 + c];
        us8 g2 = cur[(long)(int)(p2 & 0x3FFFF) * 8 + c];
        us8 g3 = cur[(long)(int)(p3 & 0x3FFFF) * 8 + c];
        float v0 = __int_as_float((int)(p0 >> 32));
        float v1 = __int_as_float((int)(p1 >> 32));
        float v2 = __int_as_float((int)(p2 >> 32));
        float v3 = __int_as_float((int)(p3 >> 32));
#pragma unroll
        for (int j = 0; j < 8; ++j)
            r[j] += v0 * bf2f(g0[j]) + v1 * bf2f(g1[j])
                  + v2 * bf2f(g2[j]) + v3 * bf2f(g3[j]);
    }
    for (; k < end; ++k) {
        long p0 = __builtin_nontemporal_load(pairs + k);
        us8 g0 = cur[(long)(int)(p0 & 0x3FFFF) * 8 + c];
        float v0 = __int_as_float((int)(p0 >> 32));
#pragma unroll
        for (int j = 0; j < 8; ++j) r[j] += v0 * bf2f(g0[j]);
    }
    long o8 = (long)row * 8 + c;
    us8 e1 = e1b[o8];
    us8 e2 = cur[o8];
    long oa = (long)row * 16 + c * 2;
    float4 a0 = acc[oa];
    float4 a1 = acc[oa + 1];
    a0.x = (a0.x + bf2f(e1[0]) + bf2f(e2[0]) + r[0]) * 0.25f;
    a0.y = (a0.y + bf2f(e1[1]) + bf2f(e2[1]) + r[1]) * 0.25f;
    a0.z = (a0.z + bf2f(e1[2]) + bf2f(e2[2]) + r[2]) * 0.25f;
    a0.w = (a0.w + bf2f(e1[3]) + bf2f(e2[3]) + r[3]) * 0.25f;
    a1.x = (a1.x + bf2f(e1[4]) + bf2f(e2[4]) + r[4]) * 0.25f;
    a1.y = (a1.y + bf2f(e1[5]) + bf2f(e2[5]) + r[5]) * 0.25f;
    a1.z = (a1.z + bf2f(e1[6]) + bf2f(e2[6]) + r[6]) * 0.25f;
    a1.w = (a1.w + bf2f(e1[7]) + bf2f(e2[7]) + r[7]) * 0.25f;
    acc[oa] = a0;
    acc[oa + 1] = a1;
}

// ---------------- R0 fallback (atomic scatter) for small ws ----------------

__global__ void lgcn_init(const float4* __restrict__ user_emb,
                          const float4* __restrict__ item_emb,
                          float4* __restrict__ cur, float4* __restrict__ nxt,
                          float4* __restrict__ acc) {
    int i = blockIdx.x * blockDim.x + threadIdx.x;
    if (i >= NODE_F4) return;
    float4 v = (i < USER_F4) ? user_emb[i] : item_emb[i - USER_F4];
    cur[i] = v; acc[i] = v; nxt[i] = make_float4(0.f, 0.f, 0.f, 0.f);
}

__global__ void lgcn_scatter(const int* __restrict__ src, const int* __restrict__ dst,
                             const float* __restrict__ val,
                             const float4* __restrict__ cur, float* __restrict__ nxt) {
    int tid = blockIdx.x * blockDim.x + threadIdx.x;
    int e = tid >> 4;
    if (e >= N_EDGES) return;
    int c = tid & 15;
    int s = src[e]; int d = dst[e]; float v = val[e];
    float4 m = cur[(long)s * 16 + c];
    float* p = nxt + (long)d * 64 + c * 4;
    unsafeAtomicAdd(p + 0, v * m.x);
    unsafeAtomicAdd(p + 1, v * m.y);
    unsafeAtomicAdd(p + 2, v * m.z);
    unsafeAtomicAdd(p + 3, v * m.w);
}

__global__ void lgcn_add_zero(float4* __restrict__ acc, const float4* __restrict__ nxt,
                              float4* __restrict__ other) {
    int i = blockIdx.x * blockDim.x + threadIdx.x;
    if (i >= NODE_F4) return;
    float4 a = acc[i]; float4 n = nxt[i];
    a.x += n.x; a.y += n.y; a.z += n.z; a.w += n.w;
    acc[i] = a;
    other[i] = make_float4(0.f, 0.f, 0.f, 0.f);
}

__global__ void lgcn_final(float4* __restrict__ acc, const float4* __restrict__ nxt) {
    int i = blockIdx.x * blockDim.x + threadIdx.x;
    if (i >= NODE_F4) return;
    float4 a = acc[i]; float4 n = nxt[i];
    a.x = (a.x + n.x) * 0.25f; a.y = (a.y + n.y) * 0.25f;
    a.z = (a.z + n.z) * 0.25f; a.w = (a.w + n.w) * 0.25f;
    acc[i] = a;
}

// ---------------- launch ----------------

extern "C" void kernel_launch(void* const* d_in, const int* in_sizes, int n_in,
                              void* d_out, int out_size, void* d_ws, size_t ws_size,
                              hipStream_t stream) {
    const int*    adj_src  = (const int*)d_in[2];
    const int*    adj_dst  = (const int*)d_in[3];
    const float*  adj_vals = (const float*)d_in[4];
    float* acc = (float*)d_out;

    const int BLK = 256;
    const int grid_node = (NODE_F4 + BLK - 1) / BLK;        // 9375
    const int grid_row8 = (N_NODES * 8 + BLK - 1) / BLK;    // 4688

    // workspace layout (bytes):
    //   [0, 48MB)      pairs2
    //   [48, 96MB)     pairs1; after k_sort reused: e0b (19.2) + e1b (19.2)
    //   [96, 115.2MB)  e2b
    //   [115.2MB, ...) row_ptr (150017 ints), gcnt, boff, gcur
    const size_t SZ_PAIRS = (size_t)N_EDGES * 8;             // 48,000,000
    const size_t SZ_BF    = (size_t)N_NODES * EMB * 2;       // 19,200,000
    const size_t SZ_RP    = 600320;                          // 150017 ints, padded
    const size_t SZ_B     = 4096;
    const size_t NEEDED   = 2 * SZ_PAIRS + SZ_BF + SZ_RP + 3 * SZ_B;  // ~115.8 MB

    if (ws_size >= NEEDED) {
        char* w = (char*)d_ws;
        int2* pairs2 = (int2*)(w);
        int2* pairs1 = (int2*)(w + SZ_PAIRS);
        us8*  e0b    = (us8*)(w + SZ_PAIRS);                  // aliases pairs1
        us8*  e1b    = (us8*)(w + SZ_PAIRS + SZ_BF);          // aliases pairs1
        us8*  e2b    = (us8*)(w + 2 * SZ_PAIRS);
        int*  row_ptr= (int*)(w + 2 * SZ_PAIRS + SZ_BF);
        int*  gcnt   = (int*)(w + 2 * SZ_PAIRS + SZ_BF + SZ_RP);
        int*  boff   = (int*)(w + 2 * SZ_PAIRS + SZ_BF + SZ_RP + SZ_B);
        int*  gcur   = (int*)(w + 2 * SZ_PAIRS + SZ_BF + SZ_RP + 2 * SZ_B);

        // phase 0: bucket counts -> offsets
        k_zero<<<(NBUCKETS + BLK - 1) / BLK, BLK, 0, stream>>>(gcnt, NBUCKETS);
        k_bhist<<<PART_BLOCKS, BLK, 0, stream>>>(adj_dst, gcnt);
        k_bscan<<<1, 1024, 0, stream>>>(gcnt, boff, gcur);

        // phase 1: bucket partition
        k_part<<<PART_BLOCKS, BLK, 0, stream>>>(adj_src, adj_dst, adj_vals, gcur, pairs1);

        // phase 2: per-bucket row sort -> pairs2 + row_ptr
        k_sort<<<NBUCKETS, BLK, 0, stream>>>(boff, pairs1, pairs2, row_ptr);

        // phase 3: propagation (pairs1 region reused for e0b/e1b)
        k_init<<<grid_node, BLK, 0, stream>>>((const f4v*)d_in[5], (const f4v*)d_in[6],
                                              (ushort4*)e0b, (f4v*)acc);
        k_spmm<<<grid_row8, BLK, 0, stream>>>(row_ptr, (const long*)pairs2, e0b, e1b);
        k_spmm<<<grid_row8, BLK, 0, stream>>>(row_ptr, (const long*)pairs2, e1b, e2b);
        k_spmm_fin<<<grid_row8, BLK, 0, stream>>>(row_ptr, (const long*)pairs2, e2b,
                                                  e1b, (float4*)acc);
    } else {
        // R0 fallback: atomic scatter
        const float4* user_emb = (const float4*)d_in[5];
        const float4* item_emb = (const float4*)d_in[6];
        float* ws0 = (float*)d_ws;
        float* ws1 = ws0 + (size_t)N_NODES * EMB;
        lgcn_init<<<grid_node, BLK, 0, stream>>>(user_emb, item_emb,
                                                 (float4*)ws0, (float4*)ws1, (float4*)acc);
        lgcn_scatter<<<(N_EDGES*16+BLK-1)/BLK, BLK, 0, stream>>>(adj_src, adj_dst, adj_vals,
                                                    (const float4*)ws0, ws1);
        lgcn_add_zero<<<grid_node, BLK, 0, stream>>>((float4*)acc, (const float4*)ws1, (float4*)ws0);
        lgcn_scatter<<<(N_EDGES*16+BLK-1)/BLK, BLK, 0, stream>>>(adj_src, adj_dst, adj_vals,
                                                    (const float4*)ws1, ws0);
        lgcn_add_zero<<<grid_node, BLK, 0, stream>>>((float4*)acc, (const float4*)ws0, (float4*)ws1);
        lgcn_scatter<<<(N_EDGES*16+BLK-1)/BLK, BLK, 0, stream>>>(adj_src, adj_dst, adj_vals,
                                                    (const float4*)ws0, ws1);
        lgcn_final<<<grid_node, BLK, 0, stream>>>((float4*)acc, (const float4*)ws1);
    }
}

// Round 9
// 662.855 us; speedup vs baseline: 1.1865x; 1.1865x over previous
//
#include <hip/hip_runtime.h>

// LightGCN propagation on MI355X — R8: acc-RMW elimination kept; spmm back to
// 16 lanes/row (8B gathers, 2x waves) with unroll-8 MLP; cached pair loads;
// PART_BLOCKS=256 for lower partition write amplification.
//
// R7 post-mortem: 8-lane ushort8 spmm halved wave count -> halved outstanding
// gathers -> 161 us/layer (latency-bound, VALUBusy 22%). NT on pairs2 also
// defeated LLC reuse across layers. Reverting those; keeping what worked
// (WRITE 75->18.75 MB from dropping per-layer acc RMW).
//
// Inputs: [2] adj_src (6M int), [3] adj_dst (6M int), [4] adj_vals (6M f32),
//         [5] user_emb (100000x64 f32), [6] item_emb (50000x64 f32).
// Output: [150000x64] f32 = (e0+e1+e2+e3)/4.

#define NUM_USERS 100000
#define NUM_ITEMS 50000
#define N_NODES   150000
#define EMB       64
#define N_EDGES   6000000

#define ROWS_PER_B 256
#define NBUCKETS   586                        // ceil(150000/256)
#define NROWS_PAD  (NBUCKETS * ROWS_PER_B)    // 150016
#define PART_BLOCKS 256
#define CHUNK ((N_EDGES + PART_BLOCKS - 1) / PART_BLOCKS)   // 23438

constexpr int NODE_F4 = N_NODES * EMB / 4;   // 2,400,000
constexpr int USER_F4 = NUM_USERS * EMB / 4; // 1,600,000

typedef float f4v __attribute__((ext_vector_type(4)));   // 16B clang vector

__device__ __forceinline__ float bf2f(unsigned short u) {
    union { unsigned int i; float f; } x; x.i = ((unsigned int)u) << 16; return x.f;
}
__device__ __forceinline__ unsigned short f2bf(float f) {
    union { float f; unsigned int i; } x; x.f = f;
    unsigned int b = x.i;
    return (unsigned short)((b + 0x7FFFu + ((b >> 16) & 1u)) >> 16);  // RNE
}

// ---------------- phase 0: bucket histogram + scan ----------------

__global__ void k_zero(int* __restrict__ p, int n) {
    int i = blockIdx.x * blockDim.x + threadIdx.x;
    if (i < n) p[i] = 0;
}

__global__ __launch_bounds__(256) void k_bhist(const int* __restrict__ dst,
                                               int* __restrict__ gcnt) {
    __shared__ int cnt[NBUCKETS];
    int t = threadIdx.x;
    for (int i = t; i < NBUCKETS; i += 256) cnt[i] = 0;
    __syncthreads();
    int e0 = blockIdx.x * CHUNK;
    int e1 = min(e0 + CHUNK, N_EDGES);
    int e = e0 + t;
    for (; e + 256 < e1; e += 512) {
        int b0 = __builtin_nontemporal_load(dst + e) >> 8;
        int b1 = __builtin_nontemporal_load(dst + e + 256) >> 8;
        atomicAdd(&cnt[b0], 1);               // native ds_add_u32
        atomicAdd(&cnt[b1], 1);
    }
    if (e < e1) atomicAdd(&cnt[__builtin_nontemporal_load(dst + e) >> 8], 1);
    __syncthreads();
    for (int i = t; i < NBUCKETS; i += 256)
        if (cnt[i]) atomicAdd(&gcnt[i], cnt[i]);
}

__global__ void k_bscan(const int* __restrict__ gcnt, int* __restrict__ boff,
                        int* __restrict__ gcur) {
    __shared__ int s[1024];
    int t = threadIdx.x;
    int x = (t < NBUCKETS) ? gcnt[t] : 0;
    s[t] = x;
    __syncthreads();
    for (int off = 1; off < 1024; off <<= 1) {
        int v = (t >= off) ? s[t - off] : 0;
        __syncthreads();
        s[t] += v;
        __syncthreads();
    }
    if (t < NBUCKETS) { int ex = s[t] - x; boff[t] = ex; gcur[t] = ex; }
    if (t == 0) boff[NBUCKETS] = N_EDGES;
}

// ---------------- phase 1: bucket partition ----------------
// entry: x = src | (dstLocal<<18), y = val bits

__global__ __launch_bounds__(256) void k_part(const int* __restrict__ src,
                                              const int* __restrict__ dst,
                                              const float* __restrict__ val,
                                              int* __restrict__ gcur,
                                              int2* __restrict__ pairs) {
    __shared__ int cnt[NBUCKETS];
    __shared__ int base[NBUCKETS];
    int t = threadIdx.x;
    for (int i = t; i < NBUCKETS; i += 256) cnt[i] = 0;
    __syncthreads();
    int e0 = blockIdx.x * CHUNK;
    int e1 = min(e0 + CHUNK, N_EDGES);
    {
        int e = e0 + t;
        for (; e + 256 < e1; e += 512) {
            int b0 = __builtin_nontemporal_load(dst + e) >> 8;
            int b1 = __builtin_nontemporal_load(dst + e + 256) >> 8;
            atomicAdd(&cnt[b0], 1);
            atomicAdd(&cnt[b1], 1);
        }
        if (e < e1) atomicAdd(&cnt[__builtin_nontemporal_load(dst + e) >> 8], 1);
    }
    __syncthreads();
    for (int i = t; i < NBUCKETS; i += 256) {
        int c = cnt[i];
        base[i] = c ? atomicAdd(&gcur[i], c) : 0;
        cnt[i] = 0;
    }
    __syncthreads();
    {
        int e = e0 + t;
        for (; e + 256 < e1; e += 512) {
            int d0 = __builtin_nontemporal_load(dst + e);
            int s0 = __builtin_nontemporal_load(src + e);
            float v0 = __builtin_nontemporal_load(val + e);
            int d1 = __builtin_nontemporal_load(dst + e + 256);
            int s1 = __builtin_nontemporal_load(src + e + 256);
            float v1 = __builtin_nontemporal_load(val + e + 256);
            int b0 = d0 >> 8, b1 = d1 >> 8;
            int o0 = atomicAdd(&cnt[b0], 1);
            int o1 = atomicAdd(&cnt[b1], 1);
            pairs[base[b0] + o0] = make_int2(s0 | ((d0 & 255) << 18), __float_as_int(v0));
            pairs[base[b1] + o1] = make_int2(s1 | ((d1 & 255) << 18), __float_as_int(v1));
        }
        if (e < e1) {
            int d0 = __builtin_nontemporal_load(dst + e);
            int s0 = __builtin_nontemporal_load(src + e);
            float v0 = __builtin_nontemporal_load(val + e);
            int o0 = atomicAdd(&cnt[d0 >> 8], 1);
            pairs[base[d0 >> 8] + o0] = make_int2(s0 | ((d0 & 255) << 18),
                                                  __float_as_int(v0));
        }
    }
}

// ---------------- phase 2: per-bucket row histogram + scan + placement ----------------

__global__ __launch_bounds__(256) void k_sort(const int* __restrict__ boff,
                                              const int2* __restrict__ pairs1,
                                              int2* __restrict__ pairs2,
                                              int* __restrict__ row_ptr) {
    __shared__ int cnt[ROWS_PER_B];    // counts, then cursors
    __shared__ int s[ROWS_PER_B];
    int b = blockIdx.x;
    int t = threadIdx.x;
    cnt[t] = 0;
    __syncthreads();
    int beg = boff[b], end = boff[b + 1];
    {
        int e = beg + t;
        for (; e + 256 < end; e += 512) {
            int r0 = ((unsigned)pairs1[e].x) >> 18;   // cached: reused by pass 2
            int r1 = ((unsigned)pairs1[e + 256].x) >> 18;
            atomicAdd(&cnt[r0], 1);
            atomicAdd(&cnt[r1], 1);
        }
        if (e < end) atomicAdd(&cnt[((unsigned)pairs1[e].x) >> 18], 1);
    }
    __syncthreads();
    int x = cnt[t];
    s[t] = x;
    __syncthreads();
    for (int off = 1; off < 256; off <<= 1) {
        int v = (t >= off) ? s[t - off] : 0;
        __syncthreads();
        s[t] += v;
        __syncthreads();
    }
    int ex = beg + s[t] - x;
    row_ptr[b * ROWS_PER_B + t] = ex;
    if (b == NBUCKETS - 1 && t == 255) row_ptr[NROWS_PAD] = N_EDGES;
    __syncthreads();
    cnt[t] = ex;
    __syncthreads();
    const long* p1l = (const long*)pairs1;
    {
        int e = beg + t;
        for (; e + 256 < end; e += 512) {
            long q0 = __builtin_nontemporal_load(p1l + e);          // last read: NT
            long q1 = __builtin_nontemporal_load(p1l + e + 256);
            int x0 = (int)q0, y0 = (int)(q0 >> 32);
            int x1 = (int)q1, y1 = (int)(q1 >> 32);
            int pos0 = atomicAdd(&cnt[((unsigned)x0) >> 18], 1);
            int pos1 = atomicAdd(&cnt[((unsigned)x1) >> 18], 1);
            pairs2[pos0] = make_int2(x0 & 0x3FFFF, y0);
            pairs2[pos1] = make_int2(x1 & 0x3FFFF, y1);
        }
        if (e < end) {
            long q0 = __builtin_nontemporal_load(p1l + e);
            int x0 = (int)q0, y0 = (int)(q0 >> 32);
            int pos0 = atomicAdd(&cnt[((unsigned)x0) >> 18], 1);
            pairs2[pos0] = make_int2(x0 & 0x3FFFF, y0);
        }
    }
}

// ---------------- phase 3: propagation ----------------

__global__ void k_init(const f4v* __restrict__ ue, const f4v* __restrict__ ie,
                       ushort4* __restrict__ e0b, f4v* __restrict__ acc) {
    int i = blockIdx.x * blockDim.x + threadIdx.x;
    if (i >= NODE_F4) return;
    f4v v = (i < USER_F4) ? __builtin_nontemporal_load(ue + i)
                          : __builtin_nontemporal_load(ie + i - USER_F4);
    __builtin_nontemporal_store(v, acc + i);     // re-read only in the final layer
    e0b[i] = make_ushort4(f2bf(v.x), f2bf(v.y), f2bf(v.z), f2bf(v.w));
}

// 16 lanes/row; lane owns 4 channels (8B ushort4 gather). Unroll-8: 8 pair
// loads issued, then 8 independent gathers in flight. Layers 0/1: nxt only.
__global__ __launch_bounds__(256) void k_spmm(const int* __restrict__ row_ptr,
                                              const long* __restrict__ pairs,
                                              const ushort4* __restrict__ cur,
                                              ushort4* __restrict__ nxt) {
    int tid = blockIdx.x * blockDim.x + threadIdx.x;
    int row = tid >> 4;
    if (row >= N_NODES) return;
    int c = tid & 15;
    int beg = row_ptr[row];
    int end = row_ptr[row + 1];
    float4 r = make_float4(0.f, 0.f, 0.f, 0.f);
    int k = beg;
    for (; k + 7 < end; k += 8) {
        long p[8];
        ushort4 g[8];
#pragma unroll
        for (int j = 0; j < 8; ++j) p[j] = pairs[k + j];
#pragma unroll
        for (int j = 0; j < 8; ++j) g[j] = cur[(long)(int)(p[j] & 0x3FFFF) * 16 + c];
#pragma unroll
        for (int j = 0; j < 8; ++j) {
            float v = __int_as_float((int)(p[j] >> 32));
            r.x += v * bf2f(g[j].x);
            r.y += v * bf2f(g[j].y);
            r.z += v * bf2f(g[j].z);
            r.w += v * bf2f(g[j].w);
        }
    }
    for (; k < end; ++k) {
        long p0 = pairs[k];
        ushort4 g0 = cur[(long)(int)(p0 & 0x3FFFF) * 16 + c];
        float v0 = __int_as_float((int)(p0 >> 32));
        r.x += v0 * bf2f(g0.x);
        r.y += v0 * bf2f(g0.y);
        r.z += v0 * bf2f(g0.z);
        r.w += v0 * bf2f(g0.w);
    }
    nxt[(long)row * 16 + c] = make_ushort4(f2bf(r.x), f2bf(r.y), f2bf(r.z), f2bf(r.w));
}

// Final layer: r = SpMM(e2); acc = (acc + e1 + e2 + r) * 0.25
__global__ __launch_bounds__(256) void k_spmm_fin(const int* __restrict__ row_ptr,
                                                  const long* __restrict__ pairs,
                                                  const ushort4* __restrict__ cur,  // e2b
                                                  const ushort4* __restrict__ e1b,
                                                  float4* __restrict__ acc) {
    int tid = blockIdx.x * blockDim.x + threadIdx.x;
    int row = tid >> 4;
    if (row >= N_NODES) return;
    int c = tid & 15;
    int beg = row_ptr[row];
    int end = row_ptr[row + 1];
    float4 r = make_float4(0.f, 0.f, 0.f, 0.f);
    int k = beg;
    for (; k + 7 < end; k += 8) {
        long p[8];
        ushort4 g[8];
#pragma unroll
        for (int j = 0; j < 8; ++j) p[j] = pairs[k + j];
#pragma unroll
        for (int j = 0; j < 8; ++j) g[j] = cur[(long)(int)(p[j] & 0x3FFFF) * 16 + c];
#pragma unroll
        for (int j = 0; j < 8; ++j) {
            float v = __int_as_float((int)(p[j] >> 32));
            r.x += v * bf2f(g[j].x);
            r.y += v * bf2f(g[j].y);
            r.z += v * bf2f(g[j].z);
            r.w += v * bf2f(g[j].w);
        }
    }
    for (; k < end; ++k) {
        long p0 = pairs[k];
        ushort4 g0 = cur[(long)(int)(p0 & 0x3FFFF) * 16 + c];
        float v0 = __int_as_float((int)(p0 >> 32));
        r.x += v0 * bf2f(g0.x);
        r.y += v0 * bf2f(g0.y);
        r.z += v0 * bf2f(g0.z);
        r.w += v0 * bf2f(g0.w);
    }
    long o = (long)row * 16 + c;
    ushort4 e1 = e1b[o];
    ushort4 e2 = cur[o];
    float4 a = acc[o];
    a.x = (a.x + bf2f(e1.x) + bf2f(e2.x) + r.x) * 0.25f;
    a.y = (a.y + bf2f(e1.y) + bf2f(e2.y) + r.y) * 0.25f;
    a.z = (a.z + bf2f(e1.z) + bf2f(e2.z) + r.z) * 0.25f;
    a.w = (a.w + bf2f(e1.w) + bf2f(e2.w) + r.w) * 0.25f;
    acc[o] = a;
}

// ---------------- R0 fallback (atomic scatter) for small ws ----------------

__global__ void lgcn_init(const float4* __restrict__ user_emb,
                          const float4* __restrict__ item_emb,
                          float4* __restrict__ cur, float4* __restrict__ nxt,
                          float4* __restrict__ acc) {
    int i = blockIdx.x * blockDim.x + threadIdx.x;
    if (i >= NODE_F4) return;
    float4 v = (i < USER_F4) ? user_emb[i] : item_emb[i - USER_F4];
    cur[i] = v; acc[i] = v; nxt[i] = make_float4(0.f, 0.f, 0.f, 0.f);
}

__global__ void lgcn_scatter(const int* __restrict__ src, const int* __restrict__ dst,
                             const float* __restrict__ val,
                             const float4* __restrict__ cur, float* __restrict__ nxt) {
    int tid = blockIdx.x * blockDim.x + threadIdx.x;
    int e = tid >> 4;
    if (e >= N_EDGES) return;
    int c = tid & 15;
    int s = src[e]; int d = dst[e]; float v = val[e];
    float4 m = cur[(long)s * 16 + c];
    float* p = nxt + (long)d * 64 + c * 4;
    unsafeAtomicAdd(p + 0, v * m.x);
    unsafeAtomicAdd(p + 1, v * m.y);
    unsafeAtomicAdd(p + 2, v * m.z);
    unsafeAtomicAdd(p + 3, v * m.w);
}

__global__ void lgcn_add_zero(float4* __restrict__ acc, const float4* __restrict__ nxt,
                              float4* __restrict__ other) {
    int i = blockIdx.x * blockDim.x + threadIdx.x;
    if (i >= NODE_F4) return;
    float4 a = acc[i]; float4 n = nxt[i];
    a.x += n.x; a.y += n.y; a.z += n.z; a.w += n.w;
    acc[i] = a;
    other[i] = make_float4(0.f, 0.f, 0.f, 0.f);
}

__global__ void lgcn_final(float4* __restrict__ acc, const float4* __restrict__ nxt) {
    int i = blockIdx.x * blockDim.x + threadIdx.x;
    if (i >= NODE_F4) return;
    float4 a = acc[i]; float4 n = nxt[i];
    a.x = (a.x + n.x) * 0.25f; a.y = (a.y + n.y) * 0.25f;
    a.z = (a.z + n.z) * 0.25f; a.w = (a.w + n.w) * 0.25f;
    acc[i] = a;
}

// ---------------- launch ----------------

extern "C" void kernel_launch(void* const* d_in, const int* in_sizes, int n_in,
                              void* d_out, int out_size, void* d_ws, size_t ws_size,
                              hipStream_t stream) {
    const int*    adj_src  = (const int*)d_in[2];
    const int*    adj_dst  = (const int*)d_in[3];
    const float*  adj_vals = (const float*)d_in[4];
    float* acc = (float*)d_out;

    const int BLK = 256;
    const int grid_node  = (NODE_F4 + BLK - 1) / BLK;        // 9375
    const int grid_row16 = (N_NODES * 16 + BLK - 1) / BLK;   // 9375

    // workspace layout (bytes):
    //   [0, 48MB)      pairs2
    //   [48, 96MB)     pairs1; after k_sort reused: e0b (19.2) + e1b (19.2)
    //   [96, 115.2MB)  e2b
    //   [115.2MB, ...) row_ptr (150017 ints), gcnt, boff, gcur
    const size_t SZ_PAIRS = (size_t)N_EDGES * 8;             // 48,000,000
    const size_t SZ_BF    = (size_t)N_NODES * EMB * 2;       // 19,200,000
    const size_t SZ_RP    = 600320;                          // 150017 ints, padded
    const size_t SZ_B     = 4096;
    const size_t NEEDED   = 2 * SZ_PAIRS + SZ_BF + SZ_RP + 3 * SZ_B;  // ~115.8 MB

    if (ws_size >= NEEDED) {
        char* w = (char*)d_ws;
        int2*    pairs2 = (int2*)(w);
        int2*    pairs1 = (int2*)(w + SZ_PAIRS);
        ushort4* e0b    = (ushort4*)(w + SZ_PAIRS);           // aliases pairs1
        ushort4* e1b    = (ushort4*)(w + SZ_PAIRS + SZ_BF);   // aliases pairs1
        ushort4* e2b    = (ushort4*)(w + 2 * SZ_PAIRS);
        int*  row_ptr= (int*)(w + 2 * SZ_PAIRS + SZ_BF);
        int*  gcnt   = (int*)(w + 2 * SZ_PAIRS + SZ_BF + SZ_RP);
        int*  boff   = (int*)(w + 2 * SZ_PAIRS + SZ_BF + SZ_RP + SZ_B);
        int*  gcur   = (int*)(w + 2 * SZ_PAIRS + SZ_BF + SZ_RP + 2 * SZ_B);

        // phase 0: bucket counts -> offsets
        k_zero<<<(NBUCKETS + BLK - 1) / BLK, BLK, 0, stream>>>(gcnt, NBUCKETS);
        k_bhist<<<PART_BLOCKS, BLK, 0, stream>>>(adj_dst, gcnt);
        k_bscan<<<1, 1024, 0, stream>>>(gcnt, boff, gcur);

        // phase 1: bucket partition
        k_part<<<PART_BLOCKS, BLK, 0, stream>>>(adj_src, adj_dst, adj_vals, gcur, pairs1);

        // phase 2: per-bucket row sort -> pairs2 + row_ptr
        k_sort<<<NBUCKETS, BLK, 0, stream>>>(boff, pairs1, pairs2, row_ptr);

        // phase 3: propagation (pairs1 region reused for e0b/e1b)
        k_init<<<grid_node, BLK, 0, stream>>>((const f4v*)d_in[5], (const f4v*)d_in[6],
                                              e0b, (f4v*)acc);
        k_spmm<<<grid_row16, BLK, 0, stream>>>(row_ptr, (const long*)pairs2, e0b, e1b);
        k_spmm<<<grid_row16, BLK, 0, stream>>>(row_ptr, (const long*)pairs2, e1b, e2b);
        k_spmm_fin<<<grid_row16, BLK, 0, stream>>>(row_ptr, (const long*)pairs2, e2b,
                                                   e1b, (float4*)acc);
    } else {
        // R0 fallback: atomic scatter
        const float4* user_emb = (const float4*)d_in[5];
        const float4* item_emb = (const float4*)d_in[6];
        float* ws0 = (float*)d_ws;
        float* ws1 = ws0 + (size_t)N_NODES * EMB;
        lgcn_init<<<grid_node, BLK, 0, stream>>>(user_emb, item_emb,
                                                 (float4*)ws0, (float4*)ws1, (float4*)acc);
        lgcn_scatter<<<(N_EDGES*16+BLK-1)/BLK, BLK, 0, stream>>>(adj_src, adj_dst, adj_vals,
                                                    (const float4*)ws0, ws1);
        lgcn_add_zero<<<grid_node, BLK, 0, stream>>>((float4*)acc, (const float4*)ws1, (float4*)ws0);
        lgcn_scatter<<<(N_EDGES*16+BLK-1)/BLK, BLK, 0, stream>>>(adj_src, adj_dst, adj_vals,
                                                    (const float4*)ws1, ws0);
        lgcn_add_zero<<<grid_node, BLK, 0, stream>>>((float4*)acc, (const float4*)ws0, (float4*)ws1);
        lgcn_scatter<<<(N_EDGES*16+BLK-1)/BLK, BLK, 0, stream>>>(adj_src, adj_dst, adj_vals,
                                                    (const float4*)ws0, ws1);
        lgcn_final<<<grid_node, BLK, 0, stream>>>((float4*)acc, (const float4*)ws1);
    }
}